// Round 1
// baseline (482.586 us; speedup 1.0000x reference)
//
#include <hip/hip_runtime.h>
#include <math.h>

#define NHEADS 8
#define DHEAD  64
#define HIDDEN 512     // NHEADS*DHEAD
#define CIN    256
#define NTOK   1024    // 32*32
#define QK_SCALE 10.0f

// ---------------------------------------------------------------------------
// Generic tiled fp32 GEMM:  C[b, m, n] = sum_k W[m,k] * X[b, k, n]  (+ bias[m])
// W row-major (M x K), X row-major per batch (K x N), C row-major (M x N).
// Block: 256 threads, 64x64 tile, 4x4 micro-tile, K-tile = 16.
// Requires M%64==0, N%64==0, K%16==0.
// ---------------------------------------------------------------------------
template <int DO_BIAS>
__global__ __launch_bounds__(256)
void gemm_wx(const float* __restrict__ W, const float* __restrict__ X,
             const float* __restrict__ bias, float* __restrict__ C,
             int M, int K, int N) {
    const int b  = blockIdx.z;
    const int bm = blockIdx.y * 64;
    const int bn = blockIdx.x * 64;
    const float* Xb = X + (size_t)b * K * N;
    float*       Cb = C + (size_t)b * M * N;

    __shared__ float sW[16][64];   // [k][m]
    __shared__ float sX[16][68];   // [k][n] (+pad)

    const int tid = threadIdx.x;
    const int tx = tid & 15;       // n direction
    const int ty = tid >> 4;       // m direction

    float acc[4][4] = {};

    for (int k0 = 0; k0 < K; k0 += 16) {
        // --- load W tile: thread -> (m = tid>>2, kq = tid&3), float4 along k
        {
            const int m  = tid >> 2;
            const int kq = tid & 3;
            const float4 w4 = *(const float4*)(W + (size_t)(bm + m) * K + k0 + kq * 4);
            sW[kq * 4 + 0][m] = w4.x;
            sW[kq * 4 + 1][m] = w4.y;
            sW[kq * 4 + 2][m] = w4.z;
            sW[kq * 4 + 3][m] = w4.w;
        }
        // --- load X tile: thread -> (k = tid>>4, nq = tid&15), float4 along n
        {
            const int k  = tid >> 4;
            const int nq = tid & 15;
            const float4 x4 = *(const float4*)(Xb + (size_t)(k0 + k) * N + bn + nq * 4);
            *(float4*)&sX[k][nq * 4] = x4;
        }
        __syncthreads();

        #pragma unroll
        for (int k = 0; k < 16; ++k) {
            float a[4], bv[4];
            #pragma unroll
            for (int i = 0; i < 4; ++i) a[i]  = sW[k][ty * 4 + i];
            #pragma unroll
            for (int j = 0; j < 4; ++j) bv[j] = sX[k][tx * 4 + j];
            #pragma unroll
            for (int i = 0; i < 4; ++i)
                #pragma unroll
                for (int j = 0; j < 4; ++j)
                    acc[i][j] = fmaf(a[i], bv[j], acc[i][j]);
        }
        __syncthreads();
    }

    #pragma unroll
    for (int i = 0; i < 4; ++i) {
        const int m = bm + ty * 4 + i;
        float bb = 0.0f;
        if (DO_BIAS) bb = bias[m];
        float4 o;
        o.x = acc[i][0] + bb;
        o.y = acc[i][1] + bb;
        o.z = acc[i][2] + bb;
        o.w = acc[i][3] + bb;
        *(float4*)(Cb + (size_t)m * N + bn + tx * 4) = o;
    }
}

// ---------------------------------------------------------------------------
// Row L2 norms over the token axis for q and k rows.
// qkv: (b, 1536, 1024). Channels 0..511 = q, 512..1023 = k.
// invn[b*1024 + ch] = 1 / max(||qkv[b,ch,:]||, 1e-12)  for ch in [0,1024).
// One block (256 threads) per row; each thread reads 4 floats.
// ---------------------------------------------------------------------------
__global__ __launch_bounds__(256)
void rownorm_kernel(const float* __restrict__ qkv, float* __restrict__ invn) {
    const int ch = blockIdx.x;           // 0..1023
    const int b  = blockIdx.y;           // 0..7
    const float* row = qkv + ((size_t)b * 1536 + ch) * NTOK;
    const int tid = threadIdx.x;

    const float4 v = *(const float4*)(row + tid * 4);
    float ss = v.x * v.x + v.y * v.y + v.z * v.z + v.w * v.w;

    #pragma unroll
    for (int o = 32; o > 0; o >>= 1) ss += __shfl_down(ss, o, 64);

    __shared__ float red[4];
    if ((tid & 63) == 0) red[tid >> 6] = ss;
    __syncthreads();
    if (tid == 0) {
        const float s = red[0] + red[1] + red[2] + red[3];
        const float nrm = sqrtf(s);
        invn[(size_t)b * 1024 + ch] = 1.0f / fmaxf(nrm, 1e-12f);
    }
}

// ---------------------------------------------------------------------------
// Flash-style attention, fp32.
// For each (b,h): q,k,v are (64 x 1024) slices of qkv. sim = (q*qn*SCALE)^T (k*kn),
// softmax over j, out[i,d] = sum_j P[i,j] v[d,j]. Output written as
// aout[b, h*64+d, i]  (i.e. (b, hidden, n) layout for the projection GEMM).
// Block: 256 threads (16x16), one 64-query i-tile; loop over 16 j-tiles.
// ---------------------------------------------------------------------------
__global__ __launch_bounds__(256)
void attn_fp32_kernel(const float* __restrict__ qkv, const float* __restrict__ invn,
                      float* __restrict__ aout) {
    const int bh = blockIdx.y;               // 0..63
    const int b  = bh >> 3;
    const int h  = bh & 7;
    const int i0 = blockIdx.x * 64;

    const float* qb = qkv + (size_t)b * 1536 * NTOK + (size_t)(h * DHEAD) * NTOK;
    const float* kb = qb + (size_t)HIDDEN * NTOK;
    const float* vb = kb + (size_t)HIDDEN * NTOK;
    const float* qn = invn + (size_t)b * 1024 + h * DHEAD;
    const float* kn = qn + HIDDEN;

    __shared__ float sQ [64][68];   // [d][i], q * qn * SCALE
    __shared__ float sKV[64][68];   // K phase: [d][j] (k*kn); V phase: [j][d]
    __shared__ float sP [64][68];   // [i][j] probabilities; reused for output transpose
    __shared__ float red[64][17];
    __shared__ float m_row[64], l_row[64], corr_row[64];

    const int tid = threadIdx.x;
    const int tx = tid & 15;        // j (or d) direction
    const int ty = tid >> 4;        // i direction

    // init running stats
    if (tid < 64) { m_row[tid] = -INFINITY; l_row[tid] = 0.0f; }

    // stage Q tile (scaled)
    {
        const int dg = tid >> 4;    // 0..15
        const int iq = tid & 15;
        #pragma unroll
        for (int r = 0; r < 4; ++r) {
            const int d = dg + r * 16;
            const float s = qn[d] * QK_SCALE;
            float4 q4 = *(const float4*)(qb + (size_t)d * NTOK + i0 + iq * 4);
            q4.x *= s; q4.y *= s; q4.z *= s; q4.w *= s;
            *(float4*)&sQ[d][iq * 4] = q4;
        }
    }

    float acc[4][4] = {};   // [ii][dd] : out accumulator (i = ty*4+ii, d = tx*4+dd)

    for (int jt = 0; jt < 16; ++jt) {
        const int j0 = jt * 64;

        // ---- phase A: load K tile (scaled by kn) as [d][j]
        {
            const int dg = tid >> 4;
            const int jq = tid & 15;
            #pragma unroll
            for (int r = 0; r < 4; ++r) {
                const int d = dg + r * 16;
                const float s = kn[d];
                float4 k4 = *(const float4*)(kb + (size_t)d * NTOK + j0 + jq * 4);
                k4.x *= s; k4.y *= s; k4.z *= s; k4.w *= s;
                *(float4*)&sKV[d][jq * 4] = k4;
            }
        }
        __syncthreads();

        // ---- phase B: sim tile s[4][4] = sum_d sQ[d][i] * sKV[d][j]
        float s[4][4] = {};
        for (int d = 0; d < 64; ++d) {
            float a[4], bv[4];
            #pragma unroll
            for (int i = 0; i < 4; ++i) a[i]  = sQ[d][ty * 4 + i];
            #pragma unroll
            for (int j = 0; j < 4; ++j) bv[j] = sKV[d][tx * 4 + j];
            #pragma unroll
            for (int i = 0; i < 4; ++i)
                #pragma unroll
                for (int j = 0; j < 4; ++j)
                    s[i][j] = fmaf(a[i], bv[j], s[i][j]);
        }

        // ---- phase C: local row max -> red
        #pragma unroll
        for (int i = 0; i < 4; ++i) {
            float lm = s[i][0];
            lm = fmaxf(lm, s[i][1]); lm = fmaxf(lm, s[i][2]); lm = fmaxf(lm, s[i][3]);
            red[ty * 4 + i][tx] = lm;
        }
        __syncthreads();   // also: everyone done reading sKV (K)

        // ---- phase D: update running max (wave0) + load V tile as [j][d]
        if (tid < 64) {
            const int row = tid;
            float mt = red[row][0];
            #pragma unroll
            for (int c = 1; c < 16; ++c) mt = fmaxf(mt, red[row][c]);
            const float m_old = m_row[row];
            const float m_new = fmaxf(m_old, mt);
            const float corr  = expf(m_old - m_new);
            m_row[row]    = m_new;
            corr_row[row] = corr;
            l_row[row]   *= corr;
        }
        {
            const int dg = tid >> 4;
            const int jq = tid & 15;
            #pragma unroll
            for (int r = 0; r < 4; ++r) {
                const int d = dg + r * 16;
                const float4 v4 = *(const float4*)(vb + (size_t)d * NTOK + j0 + jq * 4);
                sKV[jq * 4 + 0][d] = v4.x;
                sKV[jq * 4 + 1][d] = v4.y;
                sKV[jq * 4 + 2][d] = v4.z;
                sKV[jq * 4 + 3][d] = v4.w;
            }
        }
        __syncthreads();

        // ---- phase E: p = exp(s - m_new), write sP, row-sums -> red, rescale acc
        #pragma unroll
        for (int i = 0; i < 4; ++i) {
            const int row = ty * 4 + i;
            const float m = m_row[row];
            float ls = 0.0f;
            #pragma unroll
            for (int j = 0; j < 4; ++j) {
                const float p = expf(s[i][j] - m);
                sP[row][tx * 4 + j] = p;
                ls += p;
            }
            red[row][tx] = ls;
            const float corr = corr_row[row];
            #pragma unroll
            for (int dd = 0; dd < 4; ++dd) acc[i][dd] *= corr;
        }
        __syncthreads();

        // ---- phase F: l update (wave0) + PV GEMM
        if (tid < 64) {
            const int row = tid;
            float lsum = red[row][0];
            #pragma unroll
            for (int c = 1; c < 16; ++c) lsum += red[row][c];
            l_row[row] += lsum;
        }
        for (int j = 0; j < 64; ++j) {
            float a[4], bv[4];
            #pragma unroll
            for (int i = 0; i < 4; ++i)  a[i]  = sP[ty * 4 + i][j];
            #pragma unroll
            for (int dd = 0; dd < 4; ++dd) bv[dd] = sKV[j][tx * 4 + dd];
            #pragma unroll
            for (int i = 0; i < 4; ++i)
                #pragma unroll
                for (int dd = 0; dd < 4; ++dd)
                    acc[i][dd] = fmaf(a[i], bv[dd], acc[i][dd]);
        }
        __syncthreads();
    }

    // ---- epilogue: divide by l, transpose to [d][i] in LDS, coalesced store
    #pragma unroll
    for (int i = 0; i < 4; ++i) {
        const float inv_l = 1.0f / l_row[ty * 4 + i];
        #pragma unroll
        for (int dd = 0; dd < 4; ++dd)
            sP[tx * 4 + dd][ty * 4 + i] = acc[i][dd] * inv_l;   // sP as [d][i]
    }
    __syncthreads();

    {
        float* ab = aout + (size_t)b * HIDDEN * NTOK + (size_t)(h * DHEAD) * NTOK;
        const int dg = tid >> 4;
        const int iq = tid & 15;
        #pragma unroll
        for (int r = 0; r < 4; ++r) {
            const int d = dg + r * 16;
            const float4 o4 = *(const float4*)&sP[d][iq * 4];
            *(float4*)(ab + (size_t)d * NTOK + i0 + iq * 4) = o4;
        }
    }
}

// ---------------------------------------------------------------------------
// Launcher
// ---------------------------------------------------------------------------
extern "C" void kernel_launch(void* const* d_in, const int* in_sizes, int n_in,
                              void* d_out, int out_size, void* d_ws, size_t ws_size,
                              hipStream_t stream) {
    const float* x     = (const float*)d_in[0];   // (8, 256, 32, 32)
    const float* w_qkv = (const float*)d_in[1];   // (1536, 256)
    const float* w_out = (const float*)d_in[2];   // (256, 512)
    const float* b_out = (const float*)d_in[3];   // (256,)
    float* out = (float*)d_out;                   // (8, 256, 32, 32)

    const int B = 8;

    // workspace layout (fp32)
    float* qkv  = (float*)d_ws;                                   // 8*1536*1024
    float* invn = qkv + (size_t)B * 1536 * NTOK;                  // 8*1024
    float* aout = invn + (size_t)B * 1024;                        // 8*512*1024

    // 1) QKV projection: (1536 x 256) x (256 x 1024) per batch
    gemm_wx<0><<<dim3(NTOK / 64, 1536 / 64, B), 256, 0, stream>>>(
        w_qkv, x, nullptr, qkv, 1536, CIN, NTOK);

    // 2) L2 norms over tokens for q and k rows
    rownorm_kernel<<<dim3(1024, B), 256, 0, stream>>>(qkv, invn);

    // 3) attention
    attn_fp32_kernel<<<dim3(NTOK / 64, B * NHEADS), 256, 0, stream>>>(qkv, invn, aout);

    // 4) output projection + bias: (256 x 512) x (512 x 1024) per batch
    gemm_wx<1><<<dim3(NTOK / 64, 256 / 64, B), 256, 0, stream>>>(
        w_out, aout, b_out, out, 256, HIDDEN, NTOK);
}

// Round 2
// 370.550 us; speedup vs baseline: 1.3023x; 1.3023x over previous
//
#include <hip/hip_runtime.h>
#include <math.h>

#define NHEADS 8
#define DHEAD  64
#define HIDDEN 512     // NHEADS*DHEAD
#define CIN    256
#define NTOK   1024    // 32*32
#define QK_SCALE 10.0f
#define LOG2E 1.44269504088896f

typedef __bf16 bf16x8 __attribute__((ext_vector_type(8)));
typedef float  f32x4  __attribute__((ext_vector_type(4)));
typedef unsigned short u16x8 __attribute__((ext_vector_type(8)));

__device__ inline unsigned short f2bf(float f) {
    unsigned u = __builtin_bit_cast(unsigned, f);
    u = (u + 0x7FFFu + ((u >> 16) & 1u)) >> 16;   // RNE
    return (unsigned short)u;
}

__device__ inline bf16x8 cvt8(const float* p) {
    float4 a = *(const float4*)p;
    float4 b = *(const float4*)(p + 4);
    u16x8 t;
    t[0] = f2bf(a.x); t[1] = f2bf(a.y); t[2] = f2bf(a.z); t[3] = f2bf(a.w);
    t[4] = f2bf(b.x); t[5] = f2bf(b.y); t[6] = f2bf(b.z); t[7] = f2bf(b.w);
    return __builtin_bit_cast(bf16x8, t);
}

// ---------------------------------------------------------------------------
// Tiled fp32 GEMM:  C[b, m, n] = sum_k W[m,k] * X[b*xstride + k*N + n] (+bias)
// ---------------------------------------------------------------------------
template <int DO_BIAS>
__global__ __launch_bounds__(256)
void gemm_wx(const float* __restrict__ W, const float* __restrict__ X,
             const float* __restrict__ bias, float* __restrict__ C,
             int M, int K, int N, long xstride) {
    const int b  = blockIdx.z;
    const int bm = blockIdx.y * 64;
    const int bn = blockIdx.x * 64;
    const float* Xb = X + (size_t)b * xstride;
    float*       Cb = C + (size_t)b * M * N;

    __shared__ float sW[16][64];
    __shared__ float sX[16][68];

    const int tid = threadIdx.x;
    const int tx = tid & 15;
    const int ty = tid >> 4;

    float acc[4][4] = {};

    for (int k0 = 0; k0 < K; k0 += 16) {
        {
            const int m  = tid >> 2;
            const int kq = tid & 3;
            const float4 w4 = *(const float4*)(W + (size_t)(bm + m) * K + k0 + kq * 4);
            sW[kq * 4 + 0][m] = w4.x;
            sW[kq * 4 + 1][m] = w4.y;
            sW[kq * 4 + 2][m] = w4.z;
            sW[kq * 4 + 3][m] = w4.w;
        }
        {
            const int k  = tid >> 4;
            const int nq = tid & 15;
            const float4 x4 = *(const float4*)(Xb + (size_t)(k0 + k) * N + bn + nq * 4);
            *(float4*)&sX[k][nq * 4] = x4;
        }
        __syncthreads();

        #pragma unroll
        for (int k = 0; k < 16; ++k) {
            float a[4], bv[4];
            #pragma unroll
            for (int i = 0; i < 4; ++i) a[i]  = sW[k][ty * 4 + i];
            #pragma unroll
            for (int j = 0; j < 4; ++j) bv[j] = sX[k][tx * 4 + j];
            #pragma unroll
            for (int i = 0; i < 4; ++i)
                #pragma unroll
                for (int j = 0; j < 4; ++j)
                    acc[i][j] = fmaf(a[i], bv[j], acc[i][j]);
        }
        __syncthreads();
    }

    #pragma unroll
    for (int i = 0; i < 4; ++i) {
        const int m = bm + ty * 4 + i;
        float bb = 0.0f;
        if (DO_BIAS) bb = bias[m];
        float4 o;
        o.x = acc[i][0] + bb;
        o.y = acc[i][1] + bb;
        o.z = acc[i][2] + bb;
        o.w = acc[i][3] + bb;
        *(float4*)(Cb + (size_t)m * N + bn + tx * 4) = o;
    }
}

// ---------------------------------------------------------------------------
// Row L2 norms over tokens for q,k channels (ch 0..1023).
// ---------------------------------------------------------------------------
__global__ __launch_bounds__(256)
void rownorm_kernel(const float* __restrict__ qkv, float* __restrict__ invn) {
    const int ch = blockIdx.x;
    const int b  = blockIdx.y;
    const float* row = qkv + ((size_t)b * 1536 + ch) * NTOK;
    const int tid = threadIdx.x;

    const float4 v = *(const float4*)(row + tid * 4);
    float ss = v.x * v.x + v.y * v.y + v.z * v.z + v.w * v.w;

    #pragma unroll
    for (int o = 32; o > 0; o >>= 1) ss += __shfl_down(ss, o, 64);

    __shared__ float red[4];
    if ((tid & 63) == 0) red[tid >> 6] = ss;
    __syncthreads();
    if (tid == 0) {
        const float s = red[0] + red[1] + red[2] + red[3];
        invn[(size_t)b * 1024 + ch] = 1.0f / fmaxf(sqrtf(s), 1e-12f);
    }
}

// ---------------------------------------------------------------------------
// Transpose q,k (d-major fp32) -> token-major bf16 [bh][n][d], scale folded.
// One block: 64d x 64n tile. z=0 -> q (scale qn*10), z=1 -> k (scale kn).
// ---------------------------------------------------------------------------
__global__ __launch_bounds__(256)
void cvt_qk_kernel(const float* __restrict__ qkv, const float* __restrict__ invn,
                   unsigned short* __restrict__ qs, unsigned short* __restrict__ ks) {
    const int isK = blockIdx.z;
    const int bh  = blockIdx.y;
    const int b = bh >> 3, h = bh & 7;
    const int n0 = blockIdx.x * 64;
    const float* src = qkv + ((size_t)b * 1536 + isK * 512 + h * DHEAD) * NTOK;
    const float* nrm = invn + (size_t)b * 1024 + isK * 512 + h * DHEAD;
    unsigned short* dst = (isK ? ks : qs) + ((size_t)bh * NTOK + n0) * DHEAD;
    const float scl = isK ? 1.0f : QK_SCALE;

    __shared__ float T[64][65];
    const int t = threadIdx.x;
    {
        const int nq = t & 15, dg = t >> 4;
        #pragma unroll
        for (int rr = 0; rr < 4; ++rr) {
            const int d = dg + rr * 16;
            const float s = nrm[d] * scl;
            float4 v = *(const float4*)(src + (size_t)d * NTOK + n0 + nq * 4);
            T[d][nq * 4 + 0] = v.x * s;
            T[d][nq * 4 + 1] = v.y * s;
            T[d][nq * 4 + 2] = v.z * s;
            T[d][nq * 4 + 3] = v.w * s;
        }
    }
    __syncthreads();
    {
        const int n = t >> 2, dq = t & 3;
        alignas(16) unsigned short tmp[16];
        #pragma unroll
        for (int e = 0; e < 16; ++e)
            tmp[e] = f2bf(T[dq * 16 + e][n]);
        *(uint4*)(dst + (size_t)n * DHEAD + dq * 16)     = *(uint4*)&tmp[0];
        *(uint4*)(dst + (size_t)n * DHEAD + dq * 16 + 8) = *(uint4*)&tmp[8];
    }
}

// ---------------------------------------------------------------------------
// MFMA flash attention. Each wave owns 16 query rows; no barriers in the loop.
// qs/ks: [bh][n][d] bf16 (scales folded). V read fp32 d-major from qkv and
// converted in-flight. Output written into the q-fp32 region of qkv (aliased),
// layout [b][1536][1024] channels 0..511.
// ---------------------------------------------------------------------------
__global__ __launch_bounds__(256)
void attn_mfma_kernel(const unsigned short* __restrict__ qs,
                      const unsigned short* __restrict__ ks,
                      float* qkv) {
    const int hw = blockIdx.x;
    const int virt = (hw & 7) * 128 + (hw >> 3);   // XCD-chunked swizzle (1024%8==0)
    const int bh = virt >> 4;
    const int it = virt & 15;
    const int b = bh >> 3, h = bh & 7;

    const int lane = threadIdx.x & 63;
    const int wave = threadIdx.x >> 6;
    const int lo = lane & 15;
    const int hi = lane >> 4;
    const int iw = it * 64 + wave * 16;

    const unsigned short* qbh = qs + (size_t)bh * NTOK * DHEAD;
    const unsigned short* kbh = ks + (size_t)bh * NTOK * DHEAD;
    const float* vbh = qkv + ((size_t)b * 1536 + 1024 + h * DHEAD) * NTOK;

    __shared__ unsigned short Plds[4][1024];   // 16x64 bf16 per wave, XOR-swizzled
    __shared__ float Tlds[4][64][20];          // epilogue transpose
    char* pbase = (char*)&Plds[wave][0];

    // Q fragments (once)
    bf16x8 aQ0, aQ1;
    {
        const unsigned short* qp = qbh + (size_t)(iw + lo) * DHEAD + hi * 8;
        aQ0 = *(const bf16x8*)qp;
        aQ1 = *(const bf16x8*)(qp + 32);
    }

    float m_r[4], l_r[4];
    #pragma unroll
    for (int r = 0; r < 4; ++r) { m_r[r] = -INFINITY; l_r[r] = 0.0f; }
    f32x4 acc[4];
    #pragma unroll
    for (int ds = 0; ds < 4; ++ds) acc[ds] = (f32x4){0.f, 0.f, 0.f, 0.f};

    for (int jt = 0; jt < 16; ++jt) {
        const int j0 = jt * 64;

        // --- QK^T: sim 16x64 per wave
        f32x4 s[4];
        #pragma unroll
        for (int js = 0; js < 4; ++js) {
            const unsigned short* kp = kbh + (size_t)(j0 + js * 16 + lo) * DHEAD + hi * 8;
            bf16x8 bK0 = *(const bf16x8*)kp;
            bf16x8 bK1 = *(const bf16x8*)(kp + 32);
            f32x4 c = (f32x4){0.f, 0.f, 0.f, 0.f};
            c = __builtin_amdgcn_mfma_f32_16x16x32_bf16(aQ0, bK0, c, 0, 0, 0);
            c = __builtin_amdgcn_mfma_f32_16x16x32_bf16(aQ1, bK1, c, 0, 0, 0);
            s[js] = c;
        }

        // --- online softmax (rows = hi*4+r, reduce over low-4 lane bits)
        float mt[4];
        #pragma unroll
        for (int r = 0; r < 4; ++r)
            mt[r] = fmaxf(fmaxf(s[0][r], s[1][r]), fmaxf(s[2][r], s[3][r]));
        #pragma unroll
        for (int off = 1; off < 16; off <<= 1)
            #pragma unroll
            for (int r = 0; r < 4; ++r)
                mt[r] = fmaxf(mt[r], __shfl_xor(mt[r], off, 64));

        float corr[4];
        #pragma unroll
        for (int r = 0; r < 4; ++r) {
            const float mn = fmaxf(m_r[r], mt[r]);
            corr[r] = exp2f((m_r[r] - mn) * LOG2E);
            m_r[r] = mn;
        }
        float rs[4] = {0.f, 0.f, 0.f, 0.f};
        #pragma unroll
        for (int js = 0; js < 4; ++js)
            #pragma unroll
            for (int r = 0; r < 4; ++r) {
                const float p = exp2f((s[js][r] - m_r[r]) * LOG2E);
                s[js][r] = p;
                rs[r] += p;
            }
        #pragma unroll
        for (int off = 1; off < 16; off <<= 1)
            #pragma unroll
            for (int r = 0; r < 4; ++r)
                rs[r] += __shfl_xor(rs[r], off, 64);
        #pragma unroll
        for (int r = 0; r < 4; ++r) l_r[r] = l_r[r] * corr[r] + rs[r];
        #pragma unroll
        for (int ds = 0; ds < 4; ++ds)
            #pragma unroll
            for (int r = 0; r < 4; ++r)
                acc[ds][r] *= corr[r];

        // --- P -> LDS (bf16, swizzled); rows hi*4+r, cols js*16+lo
        #pragma unroll
        for (int js = 0; js < 4; ++js)
            #pragma unroll
            for (int r = 0; r < 4; ++r) {
                const int row = hi * 4 + r;
                const int byte = (row * 128 + (js * 16 + lo) * 2) ^ ((row & 7) << 4);
                *(unsigned short*)(pbase + byte) = f2bf(s[js][r]);
            }

        // --- P A-fragments: row=lo, k = kk*32 + hi*8 + e
        bf16x8 aP0, aP1;
        {
            const int swz = (lo & 7) << 4;
            aP0 = *(const bf16x8*)(pbase + ((lo * 128 + hi * 16) ^ swz));
            aP1 = *(const bf16x8*)(pbase + ((lo * 128 + 64 + hi * 16) ^ swz));
        }

        // --- PV: B[k=j][n=d] from fp32 V, converted in-flight
        #pragma unroll
        for (int ds = 0; ds < 4; ++ds) {
            const float* vp0 = vbh + (size_t)(ds * 16 + lo) * NTOK + j0 + hi * 8;
            bf16x8 bV0 = cvt8(vp0);
            bf16x8 bV1 = cvt8(vp0 + 32);
            acc[ds] = __builtin_amdgcn_mfma_f32_16x16x32_bf16(aP0, bV0, acc[ds], 0, 0, 0);
            acc[ds] = __builtin_amdgcn_mfma_f32_16x16x32_bf16(aP1, bV1, acc[ds], 0, 0, 0);
        }
    }

    // --- epilogue: 1/l, transpose via LDS, coalesced 64B/lane store
    float invl[4];
    #pragma unroll
    for (int r = 0; r < 4; ++r) invl[r] = 1.0f / l_r[r];
    #pragma unroll
    for (int ds = 0; ds < 4; ++ds)
        #pragma unroll
        for (int r = 0; r < 4; ++r)
            Tlds[wave][ds * 16 + lo][hi * 4 + r] = acc[ds][r] * invl[r];
    __syncthreads();

    {
        float* dstp = qkv + ((size_t)b * 1536 + h * DHEAD + lane) * NTOK + iw;
        #pragma unroll
        for (int q = 0; q < 4; ++q) {
            float4 o;
            o.x = Tlds[wave][lane][q * 4 + 0];
            o.y = Tlds[wave][lane][q * 4 + 1];
            o.z = Tlds[wave][lane][q * 4 + 2];
            o.w = Tlds[wave][lane][q * 4 + 3];
            *(float4*)(dstp + q * 4) = o;
        }
    }
}

// ---------------------------------------------------------------------------
// Launcher. WS layout (67.1 MB, same footprint as round 1):
//   qkv fp32 [8][1536][1024]   (q-region reused as attention output)
//   invn fp32 [8][1024]
//   qs, ks bf16 [64][1024][64]
// ---------------------------------------------------------------------------
extern "C" void kernel_launch(void* const* d_in, const int* in_sizes, int n_in,
                              void* d_out, int out_size, void* d_ws, size_t ws_size,
                              hipStream_t stream) {
    const float* x     = (const float*)d_in[0];
    const float* w_qkv = (const float*)d_in[1];
    const float* w_out = (const float*)d_in[2];
    const float* b_out = (const float*)d_in[3];
    float* out = (float*)d_out;

    float* qkv  = (float*)d_ws;
    float* invn = qkv + (size_t)8 * 1536 * NTOK;
    unsigned short* qs = (unsigned short*)(invn + 8 * 1024);
    unsigned short* ks = qs + (size_t)64 * NTOK * DHEAD;

    // 1) QKV projection (fp32)
    gemm_wx<0><<<dim3(16, 24, 8), 256, 0, stream>>>(
        w_qkv, x, nullptr, qkv, 1536, CIN, NTOK, (long)CIN * NTOK);

    // 2) token-axis L2 norms for q,k
    rownorm_kernel<<<dim3(1024, 8), 256, 0, stream>>>(qkv, invn);

    // 3) transpose+scale+convert q,k to bf16 token-major
    cvt_qk_kernel<<<dim3(16, 64, 2), 256, 0, stream>>>(qkv, invn, qs, ks);

    // 4) MFMA flash attention (writes into q-region of qkv)
    attn_mfma_kernel<<<1024, 256, 0, stream>>>(qs, ks, qkv);

    // 5) output projection + bias (reads aliased q-region, stride 1536*1024)
    gemm_wx<1><<<dim3(16, 4, 8), 256, 0, stream>>>(
        w_out, qkv, b_out, out, 256, HIDDEN, NTOK, (long)1536 * NTOK);
}

// Round 3
// 293.437 us; speedup vs baseline: 1.6446x; 1.2628x over previous
//
#include <hip/hip_runtime.h>
#include <math.h>

#define NHEADS 8
#define DHEAD  64
#define HIDDEN 512     // NHEADS*DHEAD
#define CIN    256
#define NTOK   1024    // 32*32
#define QK_SCALE 10.0f
#define LOG2E 1.44269504088896f

typedef __bf16 bf16x8 __attribute__((ext_vector_type(8)));
typedef float  f32x4  __attribute__((ext_vector_type(4)));
typedef unsigned short u16x8 __attribute__((ext_vector_type(8)));

__device__ inline unsigned short f2bf(float f) {
    unsigned u = __builtin_bit_cast(unsigned, f);
    u = (u + 0x7FFFu + ((u >> 16) & 1u)) >> 16;   // RNE
    return (unsigned short)u;
}

__device__ inline bf16x8 cvt8(const float* p) {
    float4 a = *(const float4*)p;
    float4 b = *(const float4*)(p + 4);
    u16x8 t;
    t[0] = f2bf(a.x); t[1] = f2bf(a.y); t[2] = f2bf(a.z); t[3] = f2bf(a.w);
    t[4] = f2bf(b.x); t[5] = f2bf(b.y); t[6] = f2bf(b.z); t[7] = f2bf(b.w);
    return __builtin_bit_cast(bf16x8, t);
}

// ---------------------------------------------------------------------------
// Tiled fp32 GEMM:  C[b, m, n] = sum_k W[m,k] * X[b*xstride + k*N + n] (+bias)
// ---------------------------------------------------------------------------
template <int DO_BIAS>
__global__ __launch_bounds__(256)
void gemm_wx(const float* __restrict__ W, const float* __restrict__ X,
             const float* __restrict__ bias, float* __restrict__ C,
             int M, int K, int N, long xstride) {
    const int b  = blockIdx.z;
    const int bm = blockIdx.y * 64;
    const int bn = blockIdx.x * 64;
    const float* Xb = X + (size_t)b * xstride;
    float*       Cb = C + (size_t)b * M * N;

    __shared__ float sW[16][64];
    __shared__ float sX[16][68];

    const int tid = threadIdx.x;
    const int tx = tid & 15;
    const int ty = tid >> 4;

    float acc[4][4] = {};

    for (int k0 = 0; k0 < K; k0 += 16) {
        {
            const int m  = tid >> 2;
            const int kq = tid & 3;
            const float4 w4 = *(const float4*)(W + (size_t)(bm + m) * K + k0 + kq * 4);
            sW[kq * 4 + 0][m] = w4.x;
            sW[kq * 4 + 1][m] = w4.y;
            sW[kq * 4 + 2][m] = w4.z;
            sW[kq * 4 + 3][m] = w4.w;
        }
        {
            const int k  = tid >> 4;
            const int nq = tid & 15;
            const float4 x4 = *(const float4*)(Xb + (size_t)(k0 + k) * N + bn + nq * 4);
            *(float4*)&sX[k][nq * 4] = x4;
        }
        __syncthreads();

        #pragma unroll
        for (int k = 0; k < 16; ++k) {
            float a[4], bv[4];
            #pragma unroll
            for (int i = 0; i < 4; ++i) a[i]  = sW[k][ty * 4 + i];
            #pragma unroll
            for (int j = 0; j < 4; ++j) bv[j] = sX[k][tx * 4 + j];
            #pragma unroll
            for (int i = 0; i < 4; ++i)
                #pragma unroll
                for (int j = 0; j < 4; ++j)
                    acc[i][j] = fmaf(a[i], bv[j], acc[i][j]);
        }
        __syncthreads();
    }

    #pragma unroll
    for (int i = 0; i < 4; ++i) {
        const int m = bm + ty * 4 + i;
        float bb = 0.0f;
        if (DO_BIAS) bb = bias[m];
        float4 o;
        o.x = acc[i][0] + bb;
        o.y = acc[i][1] + bb;
        o.z = acc[i][2] + bb;
        o.w = acc[i][3] + bb;
        *(float4*)(Cb + (size_t)m * N + bn + tx * 4) = o;
    }
}

// ---------------------------------------------------------------------------
// Row L2 norms over tokens for q,k channels (ch 0..1023).
// ---------------------------------------------------------------------------
__global__ __launch_bounds__(256)
void rownorm_kernel(const float* __restrict__ qkv, float* __restrict__ invn) {
    const int ch = blockIdx.x;
    const int b  = blockIdx.y;
    const float* row = qkv + ((size_t)b * 1536 + ch) * NTOK;
    const int tid = threadIdx.x;

    const float4 v = *(const float4*)(row + tid * 4);
    float ss = v.x * v.x + v.y * v.y + v.z * v.z + v.w * v.w;

    #pragma unroll
    for (int o = 32; o > 0; o >>= 1) ss += __shfl_down(ss, o, 64);

    __shared__ float red[4];
    if ((tid & 63) == 0) red[tid >> 6] = ss;
    __syncthreads();
    if (tid == 0) {
        const float s = red[0] + red[1] + red[2] + red[3];
        invn[(size_t)b * 1024 + ch] = 1.0f / fmaxf(sqrtf(s), 1e-12f);
    }
}

// ---------------------------------------------------------------------------
// Transpose q,k (d-major fp32) -> token-major bf16 [bh][n][d], scale folded.
// ---------------------------------------------------------------------------
__global__ __launch_bounds__(256)
void cvt_qk_kernel(const float* __restrict__ qkv, const float* __restrict__ invn,
                   unsigned short* __restrict__ qs, unsigned short* __restrict__ ks) {
    const int isK = blockIdx.z;
    const int bh  = blockIdx.y;
    const int b = bh >> 3, h = bh & 7;
    const int n0 = blockIdx.x * 64;
    const float* src = qkv + ((size_t)b * 1536 + isK * 512 + h * DHEAD) * NTOK;
    const float* nrm = invn + (size_t)b * 1024 + isK * 512 + h * DHEAD;
    unsigned short* dst = (isK ? ks : qs) + ((size_t)bh * NTOK + n0) * DHEAD;
    const float scl = isK ? 1.0f : QK_SCALE;

    __shared__ float T[64][65];
    const int t = threadIdx.x;
    {
        const int nq = t & 15, dg = t >> 4;
        #pragma unroll
        for (int rr = 0; rr < 4; ++rr) {
            const int d = dg + rr * 16;
            const float s = nrm[d] * scl;
            float4 v = *(const float4*)(src + (size_t)d * NTOK + n0 + nq * 4);
            T[d][nq * 4 + 0] = v.x * s;
            T[d][nq * 4 + 1] = v.y * s;
            T[d][nq * 4 + 2] = v.z * s;
            T[d][nq * 4 + 3] = v.w * s;
        }
    }
    __syncthreads();
    {
        const int n = t >> 2, dq = t & 3;
        alignas(16) unsigned short tmp[16];
        #pragma unroll
        for (int e = 0; e < 16; ++e)
            tmp[e] = f2bf(T[dq * 16 + e][n]);
        *(uint4*)(dst + (size_t)n * DHEAD + dq * 16)     = *(uint4*)&tmp[0];
        *(uint4*)(dst + (size_t)n * DHEAD + dq * 16 + 8) = *(uint4*)&tmp[8];
    }
}

// ---------------------------------------------------------------------------
// Convert V (fp32, d-major, qkv channels 1024..1535) -> bf16 in the dead
// fp32-K region (channels 512..1023). Layout preserved: [b][h*64+d][n].
// Must run AFTER cvt_qk_kernel (which reads fp32 K).
// ---------------------------------------------------------------------------
__global__ __launch_bounds__(256)
void cvt_v_kernel(float* qkv) {
    const size_t gid = (size_t)blockIdx.x * 256 + threadIdx.x;
    const size_t e   = gid * 8;                 // 8 elements per thread
    const int    b   = (int)(e >> 19);          // 512*1024 = 2^19 per batch
    const size_t rem = e & ((512u * 1024u) - 1);
    const float* src = qkv + ((size_t)b * 1536 + 1024) * NTOK + rem;
    unsigned short* dst = (unsigned short*)(qkv + ((size_t)b * 1536 + 512) * NTOK) + rem;
    const bf16x8 v = cvt8(src);
    *(bf16x8*)dst = v;
}

// ---------------------------------------------------------------------------
// MFMA flash attention. Each wave owns 32 query rows (2 Q fragments); no
// barriers in the main loop. qs/ks: [bh][n][d] bf16 (scales folded).
// V: bf16 [b][h*64+d][n] aliased in qkv's k region. Output -> q region.
// ---------------------------------------------------------------------------
__global__ __launch_bounds__(256)
void attn_mfma_kernel(const unsigned short* __restrict__ qs,
                      const unsigned short* __restrict__ ks,
                      float* qkv) {
    const int hw = blockIdx.x;                  // 512 blocks
    const int virt = (hw & 7) * 64 + (hw >> 3); // XCD-chunked: each bh on one XCD
    const int bh = virt >> 3;
    const int it = virt & 7;
    const int b = bh >> 3, h = bh & 7;

    const int lane = threadIdx.x & 63;
    const int wave = threadIdx.x >> 6;
    const int lo = lane & 15;
    const int hi = lane >> 4;
    const int iw = it * 128 + wave * 32;

    const unsigned short* qbh = qs + (size_t)bh * NTOK * DHEAD;
    const unsigned short* kbh = ks + (size_t)bh * NTOK * DHEAD;
    const unsigned short* vbh =
        (const unsigned short*)(qkv + ((size_t)b * 1536 + 512) * NTOK)
        + (size_t)(h * DHEAD) * NTOK;           // bf16 [d][n]

    __shared__ unsigned short Plds[4][2048];    // 32x64 bf16 per wave, swizzled
    __shared__ float Tlds[4][64][20];           // epilogue transpose (per-f reuse)
    char* pbase = (char*)&Plds[wave][0];

    // Q fragments (once): frag f covers rows iw+f*16 .. +15
    bf16x8 aQ[2][2];
    #pragma unroll
    for (int f = 0; f < 2; ++f) {
        const unsigned short* qp = qbh + (size_t)(iw + f * 16 + lo) * DHEAD + hi * 8;
        aQ[f][0] = *(const bf16x8*)qp;
        aQ[f][1] = *(const bf16x8*)(qp + 32);
    }

    float m_r[2][4], l_r[2][4];
    #pragma unroll
    for (int f = 0; f < 2; ++f)
        #pragma unroll
        for (int r = 0; r < 4; ++r) { m_r[f][r] = -INFINITY; l_r[f][r] = 0.0f; }
    f32x4 acc[2][4];
    #pragma unroll
    for (int f = 0; f < 2; ++f)
        #pragma unroll
        for (int ds = 0; ds < 4; ++ds) acc[f][ds] = (f32x4){0.f, 0.f, 0.f, 0.f};

    for (int jt = 0; jt < 16; ++jt) {
        const int j0 = jt * 64;

        // --- V fragment loads issued EARLY (independent of softmax)
        bf16x8 bV[4][2];
        #pragma unroll
        for (int ds = 0; ds < 4; ++ds) {
            const unsigned short* vp = vbh + (size_t)(ds * 16 + lo) * NTOK + j0 + hi * 8;
            bV[ds][0] = *(const bf16x8*)vp;
            bV[ds][1] = *(const bf16x8*)(vp + 32);
        }

        // --- QK^T: sim 32x64 per wave (2 frags)
        f32x4 s[2][4];
        #pragma unroll
        for (int js = 0; js < 4; ++js) {
            const unsigned short* kp = kbh + (size_t)(j0 + js * 16 + lo) * DHEAD + hi * 8;
            const bf16x8 bK0 = *(const bf16x8*)kp;
            const bf16x8 bK1 = *(const bf16x8*)(kp + 32);
            __builtin_amdgcn_s_setprio(1);
            #pragma unroll
            for (int f = 0; f < 2; ++f) {
                f32x4 c = (f32x4){0.f, 0.f, 0.f, 0.f};
                c = __builtin_amdgcn_mfma_f32_16x16x32_bf16(aQ[f][0], bK0, c, 0, 0, 0);
                c = __builtin_amdgcn_mfma_f32_16x16x32_bf16(aQ[f][1], bK1, c, 0, 0, 0);
                s[f][js] = c;
            }
            __builtin_amdgcn_s_setprio(0);
        }

        // --- online softmax (per frag; rows hi*4+r, reduce over low-4 lane bits)
        #pragma unroll
        for (int f = 0; f < 2; ++f) {
            float mt[4];
            #pragma unroll
            for (int r = 0; r < 4; ++r)
                mt[r] = fmaxf(fmaxf(s[f][0][r], s[f][1][r]), fmaxf(s[f][2][r], s[f][3][r]));
            #pragma unroll
            for (int off = 1; off < 16; off <<= 1)
                #pragma unroll
                for (int r = 0; r < 4; ++r)
                    mt[r] = fmaxf(mt[r], __shfl_xor(mt[r], off, 64));

            float corr[4];
            #pragma unroll
            for (int r = 0; r < 4; ++r) {
                const float mn = fmaxf(m_r[f][r], mt[r]);
                corr[r] = __builtin_amdgcn_exp2f((m_r[f][r] - mn) * LOG2E);
                m_r[f][r] = mn;
            }
            float rs[4] = {0.f, 0.f, 0.f, 0.f};
            #pragma unroll
            for (int js = 0; js < 4; ++js)
                #pragma unroll
                for (int r = 0; r < 4; ++r) {
                    const float p = __builtin_amdgcn_exp2f((s[f][js][r] - m_r[f][r]) * LOG2E);
                    s[f][js][r] = p;
                    rs[r] += p;
                }
            #pragma unroll
            for (int off = 1; off < 16; off <<= 1)
                #pragma unroll
                for (int r = 0; r < 4; ++r)
                    rs[r] += __shfl_xor(rs[r], off, 64);
            #pragma unroll
            for (int r = 0; r < 4; ++r) l_r[f][r] = l_r[f][r] * corr[r] + rs[r];
            #pragma unroll
            for (int ds = 0; ds < 4; ++ds)
                #pragma unroll
                for (int r = 0; r < 4; ++r)
                    acc[f][ds][r] *= corr[r];

            // P -> LDS (bf16, swizzled); rows f*16+hi*4+r, cols js*16+lo
            #pragma unroll
            for (int js = 0; js < 4; ++js)
                #pragma unroll
                for (int r = 0; r < 4; ++r) {
                    const int row = f * 16 + hi * 4 + r;
                    const int byte = (row * 128 + (js * 16 + lo) * 2) ^ ((row & 7) << 4);
                    *(unsigned short*)(pbase + byte) = f2bf(s[f][js][r]);
                }
        }

        // --- P A-fragments + PV
        bf16x8 aP[2][2];
        #pragma unroll
        for (int f = 0; f < 2; ++f) {
            const int row = f * 16 + lo;
            const int swz = (lo & 7) << 4;
            aP[f][0] = *(const bf16x8*)(pbase + ((row * 128 + hi * 16) ^ swz));
            aP[f][1] = *(const bf16x8*)(pbase + ((row * 128 + 64 + hi * 16) ^ swz));
        }
        __builtin_amdgcn_s_setprio(1);
        #pragma unroll
        for (int ds = 0; ds < 4; ++ds)
            #pragma unroll
            for (int f = 0; f < 2; ++f) {
                acc[f][ds] = __builtin_amdgcn_mfma_f32_16x16x32_bf16(aP[f][0], bV[ds][0], acc[f][ds], 0, 0, 0);
                acc[f][ds] = __builtin_amdgcn_mfma_f32_16x16x32_bf16(aP[f][1], bV[ds][1], acc[f][ds], 0, 0, 0);
            }
        __builtin_amdgcn_s_setprio(0);
    }

    // --- epilogue: 1/l, per-frag transpose via LDS, 64B-chunk stores
    #pragma unroll
    for (int f = 0; f < 2; ++f) {
        float invl[4];
        #pragma unroll
        for (int r = 0; r < 4; ++r) invl[r] = 1.0f / l_r[f][r];
        #pragma unroll
        for (int ds = 0; ds < 4; ++ds)
            #pragma unroll
            for (int r = 0; r < 4; ++r)
                Tlds[wave][ds * 16 + lo][hi * 4 + r] = acc[f][ds][r] * invl[r];
        // wave-synchronous: same wave wrote, same wave reads
        #pragma unroll
        for (int c = 0; c < 4; ++c) {
            const int d  = c * 16 + (lane >> 2);
            const int iq = lane & 3;
            float4 o;
            o.x = Tlds[wave][d][iq * 4 + 0];
            o.y = Tlds[wave][d][iq * 4 + 1];
            o.z = Tlds[wave][d][iq * 4 + 2];
            o.w = Tlds[wave][d][iq * 4 + 3];
            *(float4*)(qkv + ((size_t)b * 1536 + h * DHEAD + d) * NTOK + iw + f * 16 + iq * 4) = o;
        }
    }
}

// ---------------------------------------------------------------------------
// Launcher. WS layout (67.1 MB):
//   qkv fp32 [8][1536][1024]  (q-region -> attn out; k-region -> bf16 V)
//   invn fp32 [8][1024]
//   qs, ks bf16 [64][1024][64]
// ---------------------------------------------------------------------------
extern "C" void kernel_launch(void* const* d_in, const int* in_sizes, int n_in,
                              void* d_out, int out_size, void* d_ws, size_t ws_size,
                              hipStream_t stream) {
    const float* x     = (const float*)d_in[0];
    const float* w_qkv = (const float*)d_in[1];
    const float* w_out = (const float*)d_in[2];
    const float* b_out = (const float*)d_in[3];
    float* out = (float*)d_out;

    float* qkv  = (float*)d_ws;
    float* invn = qkv + (size_t)8 * 1536 * NTOK;
    unsigned short* qs = (unsigned short*)(invn + 8 * 1024);
    unsigned short* ks = qs + (size_t)64 * NTOK * DHEAD;

    // 1) QKV projection (fp32)
    gemm_wx<0><<<dim3(16, 24, 8), 256, 0, stream>>>(
        w_qkv, x, nullptr, qkv, 1536, CIN, NTOK, (long)CIN * NTOK);

    // 2) token-axis L2 norms for q,k
    rownorm_kernel<<<dim3(1024, 8), 256, 0, stream>>>(qkv, invn);

    // 3) transpose+scale+convert q,k to bf16 token-major
    cvt_qk_kernel<<<dim3(16, 64, 2), 256, 0, stream>>>(qkv, invn, qs, ks);

    // 4) convert V to bf16 (into dead fp32-K region) — after cvt_qk
    cvt_v_kernel<<<2048, 256, 0, stream>>>(qkv);

    // 5) MFMA flash attention (writes into q-region of qkv)
    attn_mfma_kernel<<<512, 256, 0, stream>>>(qs, ks, qkv);

    // 6) output projection + bias (reads aliased q-region, stride 1536*1024)
    gemm_wx<1><<<dim3(16, 4, 8), 256, 0, stream>>>(
        w_out, qkv, b_out, out, 256, HIDDEN, NTOK, (long)1536 * NTOK);
}

// Round 4
// 218.753 us; speedup vs baseline: 2.2061x; 1.3414x over previous
//
#include <hip/hip_runtime.h>
#include <math.h>

#define NHEADS 8
#define DHEAD  64
#define HIDDEN 512     // NHEADS*DHEAD
#define CIN    256
#define NTOK   1024    // 32*32
#define QK_SCALE 10.0f
#define LOG2E 1.44269504088896f

typedef __bf16 bf16x8 __attribute__((ext_vector_type(8)));
typedef float  f32x4  __attribute__((ext_vector_type(4)));
typedef unsigned short u16x8 __attribute__((ext_vector_type(8)));

__device__ inline unsigned short f2bf(float f) {
    unsigned u = __builtin_bit_cast(unsigned, f);
    u = (u + 0x7FFFu + ((u >> 16) & 1u)) >> 16;   // RNE
    return (unsigned short)u;
}

__device__ inline bf16x8 cvt8(const float* p) {
    float4 a = *(const float4*)p;
    float4 b = *(const float4*)(p + 4);
    u16x8 t;
    t[0] = f2bf(a.x); t[1] = f2bf(a.y); t[2] = f2bf(a.z); t[3] = f2bf(a.w);
    t[4] = f2bf(b.x); t[5] = f2bf(b.y); t[6] = f2bf(b.z); t[7] = f2bf(b.w);
    return __builtin_bit_cast(bf16x8, t);
}

// ---------------------------------------------------------------------------
// x (8,256,1024) fp32 d-major -> xt (8,1024,256) bf16 token-major.
// ---------------------------------------------------------------------------
__global__ __launch_bounds__(256)
void cvt_x_kernel(const float* __restrict__ x, unsigned short* __restrict__ xt) {
    const int b  = blockIdx.z;
    const int c0 = blockIdx.y * 64;
    const int n0 = blockIdx.x * 64;
    const float* src = x + ((size_t)b * CIN + c0) * NTOK + n0;
    unsigned short* dst = xt + ((size_t)b * NTOK + n0) * CIN + c0;

    __shared__ float T[64][65];
    const int t = threadIdx.x;
    {
        const int nq = t & 15, cg = t >> 4;
        #pragma unroll
        for (int rr = 0; rr < 4; ++rr) {
            const int c = cg + rr * 16;
            float4 v = *(const float4*)(src + (size_t)c * NTOK + nq * 4);
            T[c][nq * 4 + 0] = v.x;
            T[c][nq * 4 + 1] = v.y;
            T[c][nq * 4 + 2] = v.z;
            T[c][nq * 4 + 3] = v.w;
        }
    }
    __syncthreads();
    {
        const int n = t >> 2, cq = t & 3;
        alignas(16) unsigned short tmp[16];
        #pragma unroll
        for (int e = 0; e < 16; ++e)
            tmp[e] = f2bf(T[cq * 16 + e][n]);
        *(uint4*)(dst + (size_t)n * CIN + cq * 16)     = *(uint4*)&tmp[0];
        *(uint4*)(dst + (size_t)n * CIN + cq * 16 + 8) = *(uint4*)&tmp[8];
    }
}

// ---------------------------------------------------------------------------
// Weights fp32 -> bf16 (row-major preserved).
// ---------------------------------------------------------------------------
__global__ __launch_bounds__(256)
void cvt_w_kernel(const float* __restrict__ wq, const float* __restrict__ wo,
                  unsigned short* __restrict__ wqb, unsigned short* __restrict__ wob) {
    const size_t i = ((size_t)blockIdx.x * 256 + threadIdx.x) * 8;
    if (i < (size_t)1536 * 256) {
        *(bf16x8*)(wqb + i) = cvt8(wq + i);
    } else {
        const size_t j = i - (size_t)1536 * 256;
        *(bf16x8*)(wob + j) = cvt8(wo + j);
    }
}

// ---------------------------------------------------------------------------
// GEMM1: qkv = w_qkv (1536x256) x x (256x1024) per batch, bf16 MFMA.
// Block 256 thr = 4 waves (2m x 2n), tile 128x128, wave tile 64x64.
// Epilogues:
//   m < 1024 (q,k): token-major fp32 qt[isK][bh][n][d] + sumsq atomics to ss.
//   m >= 1024 (v):  bf16 d-major vb[b][ch][n] via per-wave LDS transpose.
// ---------------------------------------------------------------------------
__global__ __launch_bounds__(256)
void gemm1_kernel(const unsigned short* __restrict__ wqb,
                  const unsigned short* __restrict__ xt,
                  float* __restrict__ qt,
                  unsigned short* __restrict__ vb,
                  float* __restrict__ ss) {
    const int b  = blockIdx.z;
    const int bm = blockIdx.y * 128;
    const int bn = blockIdx.x * 128;
    const int wave = threadIdx.x >> 6, lane = threadIdx.x & 63;
    const int lo = lane & 15, hi = lane >> 4;
    const int wm = bm + (wave >> 1) * 64;
    const int wn = bn + (wave & 1) * 64;

    const unsigned short* Ab = wqb + (size_t)(wm + lo) * CIN + hi * 8;
    const unsigned short* Bb = xt + ((size_t)b * NTOK + wn + lo) * CIN + hi * 8;

    f32x4 acc[4][4];
    #pragma unroll
    for (int mi = 0; mi < 4; ++mi)
        #pragma unroll
        for (int ni = 0; ni < 4; ++ni) acc[mi][ni] = (f32x4){0.f, 0.f, 0.f, 0.f};

    for (int k0 = 0; k0 < CIN; k0 += 32) {
        bf16x8 a[4], bf[4];
        #pragma unroll
        for (int mi = 0; mi < 4; ++mi) a[mi]  = *(const bf16x8*)(Ab + (size_t)mi * 16 * CIN + k0);
        #pragma unroll
        for (int ni = 0; ni < 4; ++ni) bf[ni] = *(const bf16x8*)(Bb + (size_t)ni * 16 * CIN + k0);
        #pragma unroll
        for (int mi = 0; mi < 4; ++mi)
            #pragma unroll
            for (int ni = 0; ni < 4; ++ni)
                acc[mi][ni] = __builtin_amdgcn_mfma_f32_16x16x32_bf16(a[mi], bf[ni], acc[mi][ni], 0, 0, 0);
    }

    __shared__ unsigned short VL[4][32][72];

    if (bm < 1024) {
        // ---- q/k epilogue: token-major fp32 + sumsq
        const int isK = (wm >= 512) ? 1 : 0;
        const int ch0 = wm & 511;                  // multiple of 64
        const int head = ch0 >> 6;
        float* dst = qt + (((size_t)isK * 64 + b * 8 + head) * NTOK) * DHEAD;
        #pragma unroll
        for (int mi = 0; mi < 4; ++mi) {
            const int d = mi * 16 + hi * 4;
            #pragma unroll
            for (int ni = 0; ni < 4; ++ni) {
                const int n = wn + ni * 16 + lo;
                *(f32x4*)(dst + (size_t)n * DHEAD + d) = acc[mi][ni];
            }
        }
        float p[4][4];
        #pragma unroll
        for (int mi = 0; mi < 4; ++mi)
            #pragma unroll
            for (int r = 0; r < 4; ++r) {
                float s = 0.f;
                #pragma unroll
                for (int ni = 0; ni < 4; ++ni) s += acc[mi][ni][r] * acc[mi][ni][r];
                p[mi][r] = s;
            }
        #pragma unroll
        for (int off = 1; off < 16; off <<= 1)
            #pragma unroll
            for (int mi = 0; mi < 4; ++mi)
                #pragma unroll
                for (int r = 0; r < 4; ++r)
                    p[mi][r] += __shfl_xor(p[mi][r], off, 64);
        if (lo == 0) {
            #pragma unroll
            for (int mi = 0; mi < 4; ++mi)
                #pragma unroll
                for (int r = 0; r < 4; ++r)
                    atomicAdd(&ss[(size_t)b * 1024 + isK * 512 + ch0 + mi * 16 + hi * 4 + r], p[mi][r]);
        }
    } else {
        // ---- v epilogue: bf16 d-major via LDS transpose (two 32-row halves)
        const int ch0 = wm - 1024;                 // 0..511, multiple of 64
        #pragma unroll
        for (int half = 0; half < 2; ++half) {
            #pragma unroll
            for (int mm = 0; mm < 2; ++mm) {
                const int mi = half * 2 + mm;
                #pragma unroll
                for (int ni = 0; ni < 4; ++ni)
                    #pragma unroll
                    for (int r = 0; r < 4; ++r)
                        VL[wave][mm * 16 + hi * 4 + r][ni * 16 + lo] = f2bf(acc[mi][ni][r]);
            }
            // wave-synchronous readback
            #pragma unroll
            for (int i = 0; i < 4; ++i) {
                const int flat = i * 64 + lane;
                const int row = flat >> 3, c = flat & 7;
                uint4 v = *(uint4*)&VL[wave][row][c * 8];
                const int ch = ch0 + half * 32 + row;
                *(uint4*)(vb + ((size_t)b * HIDDEN + ch) * NTOK + wn + c * 8) = v;
            }
        }
    }
}

// ---------------------------------------------------------------------------
// invn = 1/max(sqrt(ss), eps)
// ---------------------------------------------------------------------------
__global__ __launch_bounds__(256)
void invn_kernel(const float* __restrict__ ss, float* __restrict__ invn) {
    const int i = blockIdx.x * 256 + threadIdx.x;
    invn[i] = 1.0f / fmaxf(sqrtf(ss[i]), 1e-12f);
}

// ---------------------------------------------------------------------------
// qt fp32 [isK][bh][n][d] -> qs/ks bf16 [bh][n][d], scaled by invn (x10 for q).
// ---------------------------------------------------------------------------
__global__ __launch_bounds__(256)
void scale_cvt_kernel(const float* __restrict__ qt, const float* __restrict__ invn,
                      unsigned short* __restrict__ qs, unsigned short* __restrict__ ks) {
    const size_t idx = ((size_t)blockIdx.x * 256 + threadIdx.x) * 8;
    const size_t half = (size_t)64 * NTOK * DHEAD;
    const int isK = idx >= half;
    const size_t rem = idx - (size_t)isK * half;
    const int bh = (int)(rem >> 16);
    const int d0 = (int)(rem & 63);
    const int b  = bh >> 3;
    const int ch = isK * 512 + (bh & 7) * 64 + d0;
    const float scl = isK ? 1.0f : QK_SCALE;

    const float* ip = qt + idx;
    float4 v0 = *(const float4*)ip;
    float4 v1 = *(const float4*)(ip + 4);
    float4 s0 = *(const float4*)(invn + (size_t)b * 1024 + ch);
    float4 s1 = *(const float4*)(invn + (size_t)b * 1024 + ch + 4);
    u16x8 t;
    t[0] = f2bf(v0.x * s0.x * scl); t[1] = f2bf(v0.y * s0.y * scl);
    t[2] = f2bf(v0.z * s0.z * scl); t[3] = f2bf(v0.w * s0.w * scl);
    t[4] = f2bf(v1.x * s1.x * scl); t[5] = f2bf(v1.y * s1.y * scl);
    t[6] = f2bf(v1.z * s1.z * scl); t[7] = f2bf(v1.w * s1.w * scl);
    *(u16x8*)((isK ? ks : qs) + rem) = t;
}

// ---------------------------------------------------------------------------
// MFMA flash attention, 32 q-rows/wave, j-block 128 (one softmax per 128 keys).
// Output: attn_t bf16 token-major [b][n][512].
// ---------------------------------------------------------------------------
__global__ __launch_bounds__(256)
void attn_mfma_kernel(const unsigned short* __restrict__ qs,
                      const unsigned short* __restrict__ ks,
                      const unsigned short* __restrict__ vb,
                      unsigned short* __restrict__ attn_t) {
    const int hw = blockIdx.x;                  // 512 blocks
    const int virt = (hw & 7) * 64 + (hw >> 3); // XCD-chunked
    const int bh = virt >> 3;
    const int it = virt & 7;
    const int b = bh >> 3, h = bh & 7;

    const int lane = threadIdx.x & 63;
    const int wave = threadIdx.x >> 6;
    const int lo = lane & 15;
    const int hi = lane >> 4;
    const int iw = it * 128 + wave * 32;

    const unsigned short* qbh = qs + (size_t)bh * NTOK * DHEAD;
    const unsigned short* kbh = ks + (size_t)bh * NTOK * DHEAD;
    const unsigned short* vbh = vb + ((size_t)b * HIDDEN + h * DHEAD) * NTOK;

    __shared__ unsigned short Plds[4][4096];    // 32 x 128 bf16 per wave, swizzled
    __shared__ float Tlds[4][16][69];
    char* pbase = (char*)&Plds[wave][0];

    bf16x8 aQ[2][2];
    #pragma unroll
    for (int f = 0; f < 2; ++f) {
        const unsigned short* qp = qbh + (size_t)(iw + f * 16 + lo) * DHEAD + hi * 8;
        aQ[f][0] = *(const bf16x8*)qp;
        aQ[f][1] = *(const bf16x8*)(qp + 32);
    }

    float m_r[2][4], l_r[2][4];
    #pragma unroll
    for (int f = 0; f < 2; ++f)
        #pragma unroll
        for (int r = 0; r < 4; ++r) { m_r[f][r] = -INFINITY; l_r[f][r] = 0.0f; }
    f32x4 acc[2][4];
    #pragma unroll
    for (int f = 0; f < 2; ++f)
        #pragma unroll
        for (int ds = 0; ds < 4; ++ds) acc[f][ds] = (f32x4){0.f, 0.f, 0.f, 0.f};

    for (int jt = 0; jt < 8; ++jt) {
        const int j0 = jt * 128;

        // --- QK^T over 128 keys
        f32x4 s[2][8];
        #pragma unroll
        for (int js = 0; js < 8; ++js) {
            const unsigned short* kp = kbh + (size_t)(j0 + js * 16 + lo) * DHEAD + hi * 8;
            const bf16x8 bK0 = *(const bf16x8*)kp;
            const bf16x8 bK1 = *(const bf16x8*)(kp + 32);
            __builtin_amdgcn_s_setprio(1);
            #pragma unroll
            for (int f = 0; f < 2; ++f) {
                f32x4 c = (f32x4){0.f, 0.f, 0.f, 0.f};
                c = __builtin_amdgcn_mfma_f32_16x16x32_bf16(aQ[f][0], bK0, c, 0, 0, 0);
                c = __builtin_amdgcn_mfma_f32_16x16x32_bf16(aQ[f][1], bK1, c, 0, 0, 0);
                s[f][js] = c;
            }
            __builtin_amdgcn_s_setprio(0);
        }

        // --- V fragment loads (hide L2 latency under softmax)
        bf16x8 bV[4][4];
        #pragma unroll
        for (int ds = 0; ds < 4; ++ds)
            #pragma unroll
            for (int jj = 0; jj < 4; ++jj)
                bV[ds][jj] = *(const bf16x8*)(vbh + (size_t)(ds * 16 + lo) * NTOK + j0 + jj * 32 + hi * 8);

        // --- online softmax over the 128-key block
        #pragma unroll
        for (int f = 0; f < 2; ++f) {
            float mt[4];
            #pragma unroll
            for (int r = 0; r < 4; ++r)
                mt[r] = fmaxf(fmaxf(fmaxf(s[f][0][r], s[f][1][r]), fmaxf(s[f][2][r], s[f][3][r])),
                              fmaxf(fmaxf(s[f][4][r], s[f][5][r]), fmaxf(s[f][6][r], s[f][7][r])));
            #pragma unroll
            for (int off = 1; off < 16; off <<= 1)
                #pragma unroll
                for (int r = 0; r < 4; ++r)
                    mt[r] = fmaxf(mt[r], __shfl_xor(mt[r], off, 64));

            float corr[4];
            #pragma unroll
            for (int r = 0; r < 4; ++r) {
                const float mn = fmaxf(m_r[f][r], mt[r]);
                corr[r] = __builtin_amdgcn_exp2f((m_r[f][r] - mn) * LOG2E);
                m_r[f][r] = mn;
            }
            float rs[4] = {0.f, 0.f, 0.f, 0.f};
            #pragma unroll
            for (int js = 0; js < 8; ++js)
                #pragma unroll
                for (int r = 0; r < 4; ++r) {
                    const float pp = __builtin_amdgcn_exp2f((s[f][js][r] - m_r[f][r]) * LOG2E);
                    s[f][js][r] = pp;
                    rs[r] += pp;
                }
            #pragma unroll
            for (int off = 1; off < 16; off <<= 1)
                #pragma unroll
                for (int r = 0; r < 4; ++r)
                    rs[r] += __shfl_xor(rs[r], off, 64);
            #pragma unroll
            for (int r = 0; r < 4; ++r) l_r[f][r] = l_r[f][r] * corr[r] + rs[r];
            #pragma unroll
            for (int ds = 0; ds < 4; ++ds)
                #pragma unroll
                for (int r = 0; r < 4; ++r)
                    acc[f][ds][r] *= corr[r];

            // P -> LDS (bf16, swizzled)
            #pragma unroll
            for (int js = 0; js < 8; ++js)
                #pragma unroll
                for (int r = 0; r < 4; ++r) {
                    const int row = f * 16 + hi * 4 + r;
                    const int byte = (row * 256 + (js * 16 + lo) * 2) ^ ((row & 7) << 4);
                    *(unsigned short*)(pbase + byte) = f2bf(s[f][js][r]);
                }
        }

        // --- P A-fragments + PV
        bf16x8 aP[2][4];
        #pragma unroll
        for (int f = 0; f < 2; ++f) {
            const int row = f * 16 + lo;
            const int swz = (lo & 7) << 4;
            #pragma unroll
            for (int jj = 0; jj < 4; ++jj)
                aP[f][jj] = *(const bf16x8*)(pbase + ((row * 256 + jj * 64 + hi * 16) ^ swz));
        }
        __builtin_amdgcn_s_setprio(1);
        #pragma unroll
        for (int ds = 0; ds < 4; ++ds)
            #pragma unroll
            for (int f = 0; f < 2; ++f)
                #pragma unroll
                for (int jj = 0; jj < 4; ++jj)
                    acc[f][ds] = __builtin_amdgcn_mfma_f32_16x16x32_bf16(aP[f][jj], bV[ds][jj], acc[f][ds], 0, 0, 0);
        __builtin_amdgcn_s_setprio(0);
    }

    // --- epilogue: 1/l, per-frag LDS transpose, token-major bf16 stores
    #pragma unroll
    for (int f = 0; f < 2; ++f) {
        float invl[4];
        #pragma unroll
        for (int r = 0; r < 4; ++r) invl[r] = 1.0f / l_r[f][r];
        #pragma unroll
        for (int ds = 0; ds < 4; ++ds)
            #pragma unroll
            for (int r = 0; r < 4; ++r)
                Tlds[wave][hi * 4 + r][ds * 16 + lo] = acc[f][ds][r] * invl[r];
        // wave-synchronous readback: lane -> (row i = lane>>2, chunk = lane&3)
        {
            const int i = lane >> 2, ck = lane & 3;
            alignas(16) unsigned short tmp[16];
            #pragma unroll
            for (int e = 0; e < 16; ++e)
                tmp[e] = f2bf(Tlds[wave][i][ck * 16 + e]);
            unsigned short* dst = attn_t + ((size_t)b * NTOK + iw + f * 16 + i) * HIDDEN + h * DHEAD + ck * 16;
            *(uint4*)dst       = *(uint4*)&tmp[0];
            *(uint4*)(dst + 8) = *(uint4*)&tmp[8];
        }
    }
}

// ---------------------------------------------------------------------------
// GEMM2: out = w_out (256x512) x attn_t^T (512x1024) + bias, bf16 MFMA.
// Block 128 thr = 2 waves (n-split), tile 64x128, wave tile 64x64.
// ---------------------------------------------------------------------------
__global__ __launch_bounds__(128)
void gemm2_kernel(const unsigned short* __restrict__ wob,
                  const unsigned short* __restrict__ attn_t,
                  const float* __restrict__ b_out,
                  float* __restrict__ out) {
    const int b  = blockIdx.z;
    const int bm = blockIdx.y * 64;
    const int bn = blockIdx.x * 128;
    const int wave = threadIdx.x >> 6, lane = threadIdx.x & 63;
    const int lo = lane & 15, hi = lane >> 4;
    const int wn = bn + wave * 64;

    const unsigned short* Ab = wob + (size_t)(bm + lo) * HIDDEN + hi * 8;
    const unsigned short* Bb = attn_t + ((size_t)b * NTOK + wn + lo) * HIDDEN + hi * 8;

    f32x4 acc[4][4];
    #pragma unroll
    for (int mi = 0; mi < 4; ++mi)
        #pragma unroll
        for (int ni = 0; ni < 4; ++ni) acc[mi][ni] = (f32x4){0.f, 0.f, 0.f, 0.f};

    for (int k0 = 0; k0 < HIDDEN; k0 += 32) {
        bf16x8 a[4], bf[4];
        #pragma unroll
        for (int mi = 0; mi < 4; ++mi) a[mi]  = *(const bf16x8*)(Ab + (size_t)mi * 16 * HIDDEN + k0);
        #pragma unroll
        for (int ni = 0; ni < 4; ++ni) bf[ni] = *(const bf16x8*)(Bb + (size_t)ni * 16 * HIDDEN + k0);
        #pragma unroll
        for (int mi = 0; mi < 4; ++mi)
            #pragma unroll
            for (int ni = 0; ni < 4; ++ni)
                acc[mi][ni] = __builtin_amdgcn_mfma_f32_16x16x32_bf16(a[mi], bf[ni], acc[mi][ni], 0, 0, 0);
    }

    __shared__ float OL[2][32][69];
    #pragma unroll
    for (int half = 0; half < 2; ++half) {
        #pragma unroll
        for (int mm = 0; mm < 2; ++mm) {
            const int mi = half * 2 + mm;
            #pragma unroll
            for (int ni = 0; ni < 4; ++ni)
                #pragma unroll
                for (int r = 0; r < 4; ++r)
                    OL[wave][mm * 16 + hi * 4 + r][ni * 16 + lo] = acc[mi][ni][r];
        }
        // wave-synchronous readback with bias
        #pragma unroll
        for (int i = 0; i < 8; ++i) {
            const int flat = i * 64 + lane;
            const int row = flat >> 4, c = flat & 15;
            float4 v = *(float4*)&OL[wave][row][c * 4];
            const int m = bm + half * 32 + row;
            const float bb = b_out[m];
            v.x += bb; v.y += bb; v.z += bb; v.w += bb;
            *(float4*)(out + ((size_t)b * CIN + m) * NTOK + wn + c * 4) = v;
        }
    }
}

// ---------------------------------------------------------------------------
// Launcher. WS layout (61.1 MB):
//  xt bf16 4.19MB | wqb 0.79 | wob 0.26 | ss 32K | invn 32K |
//  qs 8.39 | ks 8.39 | vb 8.39 | qt fp32 33.6 (attn_t bf16 8.39 aliased on qt)
// ---------------------------------------------------------------------------
extern "C" void kernel_launch(void* const* d_in, const int* in_sizes, int n_in,
                              void* d_out, int out_size, void* d_ws, size_t ws_size,
                              hipStream_t stream) {
    const float* x     = (const float*)d_in[0];
    const float* w_qkv = (const float*)d_in[1];
    const float* w_out = (const float*)d_in[2];
    const float* b_out = (const float*)d_in[3];
    float* out = (float*)d_out;

    char* ws = (char*)d_ws;
    unsigned short* xt  = (unsigned short*)(ws);
    unsigned short* wqb = (unsigned short*)(ws + 4194304);
    unsigned short* wob = (unsigned short*)(ws + 4980736);
    float*          ss  = (float*)(ws + 5242880);
    float*          inv = (float*)(ws + 5275648);
    unsigned short* qs  = (unsigned short*)(ws + 5308416);
    unsigned short* ks  = (unsigned short*)(ws + 13697024);
    unsigned short* vb  = (unsigned short*)(ws + 22085632);
    float*          qt  = (float*)(ws + 30474240);
    unsigned short* attn_t = (unsigned short*)(ws + 30474240);   // aliases qt (dead by then)

    hipMemsetAsync(ss, 0, 8 * 1024 * sizeof(float), stream);

    cvt_x_kernel<<<dim3(16, 4, 8), 256, 0, stream>>>(x, xt);
    cvt_w_kernel<<<256, 256, 0, stream>>>(w_qkv, w_out, wqb, wob);

    gemm1_kernel<<<dim3(8, 12, 8), 256, 0, stream>>>(wqb, xt, qt, vb, ss);

    invn_kernel<<<32, 256, 0, stream>>>(ss, inv);
    scale_cvt_kernel<<<4096, 256, 0, stream>>>(qt, inv, qs, ks);

    attn_mfma_kernel<<<512, 256, 0, stream>>>(qs, ks, vb, attn_t);

    gemm2_kernel<<<dim3(8, 4, 8), 128, 0, stream>>>(wob, attn_t, b_out, out);
}